// Round 15
// baseline (194.270 us; speedup 1.0000x reference)
//
#include <hip/hip_runtime.h>
#include <hip/hip_bf16.h>

typedef __bf16 bf16x8 __attribute__((ext_vector_type(8)));
typedef float  f32x4  __attribute__((ext_vector_type(4)));

// ---------------- workspace layout (bytes) ----------------
static constexpr size_t MB = 1u << 20;
static constexpr size_t HI_OFF  = 0;                                   // 1 MiB
static constexpr size_t HJ_OFF  = HI_OFF + MB;
static constexpr size_t Z_OFF   = HJ_OFF + MB;                         // 128 MiB (z2, then z3 in place)
static constexpr size_t PS_OFF  = Z_OFF + (size_t)524288 * 128 * 2;    // 4096*128*4 = 2 MiB
static constexpr size_t PQ_OFF  = PS_OFF + (size_t)4096 * 128 * 4;
static constexpr size_t S1I_OFF = PQ_OFF + (size_t)4096 * 128 * 4;     // 64*128*4 = 32 KiB each
static constexpr size_t S2I_OFF = S1I_OFF + 32768;
static constexpr size_t S1J_OFF = S2I_OFF + 32768;
static constexpr size_t S2J_OFF = S1J_OFF + 32768;
static constexpr size_t A1_OFF  = S2J_OFF + 32768;                     // 512 each
static constexpr size_t D1_OFF  = A1_OFF + 512;
static constexpr size_t A2_OFF  = D1_OFF + 512;
static constexpr size_t C2_OFF  = A2_OFF + 512;
static constexpr size_t A3_OFF  = C2_OFF + 512;
static constexpr size_t C3_OFF  = A3_OFF + 512;
static constexpr size_t AF_OFF  = C3_OFF + 512;
static constexpr size_t CF_OFF  = AF_OFF + 512;
static constexpr size_t AO_OFF  = CF_OFF + 512;
static constexpr size_t CO_OFF  = AO_OFF + 512;
static constexpr size_t W2T_OFF = CO_OFF + 512;                        // 32 KiB
static constexpr size_t W3T_OFF = W2T_OFF + 32768;
static constexpr size_t XAGG_OFF = W3T_OFF + 32768;                    // 1 MiB
static constexpr size_t Y1_OFF  = XAGG_OFF + MB;
static constexpr size_t Y2_OFF  = Y1_OFF + MB;
static constexpr size_t TPS_OFF = Y2_OFF + MB;                         // 64 KiB
static constexpr size_t TPQ_OFF = TPS_OFF + 65536;

// ---------------- K1: hi = xf@W1a, hj = xf@W1b ----------------
__global__ void build_h(const float* __restrict__ x, const float* __restrict__ coord,
                        const float* __restrict__ W1a, const float* __restrict__ W1b,
                        float* __restrict__ hi, float* __restrict__ hj)
{
    __shared__ float xr[18];
    int bl = blockIdx.x;            // b*256 + l
    int b = bl >> 8, l = bl & 255;
    int t = threadIdx.x;            // 128 = channel f
    if (t < 18)
        xr[t] = (t < 16) ? x[((size_t)b * 16 + t) * 256 + l] : coord[l * 2 + (t - 16)];
    __syncthreads();
    float ai = 0.f, aj = 0.f;
#pragma unroll
    for (int c = 0; c < 18; ++c) {
        float xv = xr[c];
        ai += xv * W1a[c * 128 + t];
        aj += xv * W1b[c * 128 + t];
    }
    hi[(size_t)bl * 128 + t] = ai;
    hj[(size_t)bl * 128 + t] = aj;
}

// ---------------- K2: per-(b,lgroup) moments of hi/hj ----------------
__global__ void stats1(const float* __restrict__ hi, const float* __restrict__ hj,
                       float* __restrict__ S1i, float* __restrict__ S2i,
                       float* __restrict__ S1j, float* __restrict__ S2j)
{
    int g = blockIdx.x;             // b*8 + lg
    int b = g >> 3, lg = g & 7;
    int f = threadIdx.x;
    float s1i = 0, s2i = 0, s1j = 0, s2j = 0;
#pragma unroll 4
    for (int i = 0; i < 32; ++i) {
        int l = lg * 32 + i;
        float vi = hi[((size_t)b * 256 + l) * 128 + f];
        float vj = hj[((size_t)b * 256 + l) * 128 + f];
        s1i += vi; s2i += vi * vi;
        s1j += vj; s2j += vj * vj;
    }
    S1i[g * 128 + f] = s1i; S2i[g * 128 + f] = s2i;
    S1j[g * 128 + f] = s1j; S2j[g * 128 + f] = s2j;
}

// ---------------- K2b: BN1 closed-form ----------------
__global__ void bn1_finalize(const float* __restrict__ S1i, const float* __restrict__ S2i,
                             const float* __restrict__ S1j, const float* __restrict__ S2j,
                             const float* __restrict__ g, const float* __restrict__ be,
                             float* __restrict__ a1, float* __restrict__ d1)
{
    int f = threadIdx.x;  // 128
    float s1i = 0, s2i = 0, s1j = 0, s2j = 0;
    float mib[8], mjb[8];
#pragma unroll
    for (int b = 0; b < 8; ++b) {
        float sb = 0, sbj = 0;
#pragma unroll
        for (int lg = 0; lg < 8; ++lg) {
            int gg = b * 8 + lg;
            sb  += S1i[gg * 128 + f]; s2i += S2i[gg * 128 + f];
            sbj += S1j[gg * 128 + f]; s2j += S2j[gg * 128 + f];
        }
        mib[b] = sb * (1.f / 256.f); mjb[b] = sbj * (1.f / 256.f);
        s1i += sb; s1j += sbj;
    }
    const float invN = 1.f / 2048.f;
    float mi = s1i * invN, mj = s1j * invN;
    float vu = s2i * invN - mi * mi;
    float vv = s2j * invN - mj * mj;
    float cr = 0.f;
#pragma unroll
    for (int b = 0; b < 8; ++b) cr += (mib[b] - mi) * (mjb[b] - mj);
    cr *= (1.f / 8.f);
    float var = vu + vv + 2.f * cr;
    float av = g[f] * rsqrtf(var + 1e-5f);
    a1[f] = av;
    d1[f] = be[f] - av * (mi + mj);   // b1 cancels (BN shift invariance)
}

// ---------------- transposed bf16 weights (parallel) ----------------
__global__ void transpose_w(const float* __restrict__ W2, const float* __restrict__ W3,
                            __bf16* __restrict__ W2t, __bf16* __restrict__ W3t)
{
    int f = blockIdx.x, k = threadIdx.x;   // Wt[f][k] = W[k][f]
    W2t[f * 128 + k] = (__bf16)W2[k * 128 + f];
    W3t[f * 128 + k] = (__bf16)W3[k * 128 + f];
}

// ============ big pairwise GEMM 1: z2 = relu(BN1(hi[l]+hj[k])) @ W2 ============
// N-sliced waves + intra-block M-split pipeline: stage rows 0-63 -> barrier ->
// [issue stage rows 64-127, compute m=0..3] -> barrier -> compute m=4..7.
__global__ __launch_bounds__(256, 4) void pair_gemm1(
    const float* __restrict__ hi, const float* __restrict__ hj,
    const float* __restrict__ a1, const float* __restrict__ d1,
    const __bf16* __restrict__ W2t,
    __bf16* __restrict__ Z, float* __restrict__ ps, float* __restrict__ pq)
{
    __shared__ __align__(16) char hA[32768];   // 128x128 bf16, XOR-swizzled

    int blk = blockIdx.x;
    int half = blk & 1;
    int bk = blk >> 1;             // b*256 + k
    int b = bk >> 8;
    int t = threadIdx.x;
    int lane = t & 63;
    int wave = t >> 6;
    int fc = (t & 15) * 8;         // staging channel chunk
    int rg = t >> 4;               // staging row group 0..15
    int cl = lane & 15;
    int kg = lane >> 4;            // 0..3
    int colbase = wave * 32;

    // B fragments (hoisted; latency overlaps staging below)
    bf16x8 Bf[2][4];
#pragma unroll
    for (int n = 0; n < 2; ++n) {
        const __bf16* wp = W2t + (colbase + n * 16 + cl) * 128 + kg * 8;
#pragma unroll
        for (int kk = 0; kk < 4; ++kk)
            Bf[n][kk] = *reinterpret_cast<const bf16x8*>(wp + kk * 32);
    }

    float a1v[8], qv[8];
    const float* hjrow = hj + (size_t)bk * 128 + fc;
    const float* d1p = d1 + fc;
    const float* a1p = a1 + fc;
#pragma unroll
    for (int j = 0; j < 8; ++j) { a1v[j] = a1p[j]; qv[j] = a1v[j] * hjrow[j] + d1p[j]; }

    const float* hib = hi + ((size_t)b * 256 + half * 128) * 128;
    // stage rows 0..63
#pragma unroll
    for (int rr = 0; rr < 64; rr += 16) {
        int row = rr + rg;
        const float* src = hib + row * 128 + fc;
        bf16x8 v;
#pragma unroll
        for (int j = 0; j < 8; ++j)
            v[j] = (__bf16)fmaxf(a1v[j] * src[j] + qv[j], 0.f);
        int byte = (row * 256 + fc * 2) ^ ((row & 7) << 4);
        *reinterpret_cast<bf16x8*>(hA + byte) = v;
    }
    __syncthreads();

    // stage rows 64..127 (disjoint LDS region; overlaps compute of m=0..3)
#pragma unroll
    for (int rr = 64; rr < 128; rr += 16) {
        int row = rr + rg;
        const float* src = hib + row * 128 + fc;
        bf16x8 v;
#pragma unroll
        for (int j = 0; j < 8; ++j)
            v[j] = (__bf16)fmaxf(a1v[j] * src[j] + qv[j], 0.f);
        int byte = (row * 256 + fc * 2) ^ ((row & 7) << 4);
        *reinterpret_cast<bf16x8*>(hA + byte) = v;
    }

    f32x4 acc[8][2] = {};
    // compute m=0..3 (rows 0..63)
#pragma unroll
    for (int kk = 0; kk < 128; kk += 32) {
        bf16x8 af[4];
#pragma unroll
        for (int m = 0; m < 4; ++m) {
            int row = m * 16 + cl;
            int byte = (row * 256 + (kk + kg * 8) * 2) ^ ((row & 7) << 4);
            af[m] = *reinterpret_cast<const bf16x8*>(hA + byte);
        }
#pragma unroll
        for (int m = 0; m < 4; ++m)
#pragma unroll
            for (int n = 0; n < 2; ++n)
                acc[m][n] = __builtin_amdgcn_mfma_f32_16x16x32_bf16(af[m], Bf[n][kk >> 5], acc[m][n], 0, 0, 0);
    }
    __syncthreads();
    // compute m=4..7 (rows 64..127)
#pragma unroll
    for (int kk = 0; kk < 128; kk += 32) {
        bf16x8 af[4];
#pragma unroll
        for (int m = 4; m < 8; ++m) {
            int row = m * 16 + cl;
            int byte = (row * 256 + (kk + kg * 8) * 2) ^ ((row & 7) << 4);
            af[m - 4] = *reinterpret_cast<const bf16x8*>(hA + byte);
        }
#pragma unroll
        for (int m = 4; m < 8; ++m)
#pragma unroll
            for (int n = 0; n < 2; ++n)
                acc[m][n] = __builtin_amdgcn_mfma_f32_16x16x32_bf16(af[m - 4], Bf[n][kk >> 5], acc[m][n], 0, 0, 0);
    }

    // epilogue: line-friendly order (both 32B halves of each 64B region back-to-back)
    __bf16* zb = Z + ((size_t)bk * 256 + half * 128) * 128;
    int r0 = kg * 4;
    float s[2] = {}, q[2] = {};
#pragma unroll
    for (int m = 0; m < 8; ++m)
#pragma unroll
        for (int r = 0; r < 4; ++r) {
            int row = m * 16 + r0 + r;
#pragma unroll
            for (int n = 0; n < 2; ++n) {
                float v = acc[m][n][r];
                zb[row * 128 + colbase + n * 16 + cl] = (__bf16)v;
                s[n] += v; q[n] += v * v;
            }
        }
#pragma unroll
    for (int n = 0; n < 2; ++n) {
        float sv = s[n], qv2 = q[n];
        sv += __shfl_xor(sv, 16); sv += __shfl_xor(sv, 32);
        qv2 += __shfl_xor(qv2, 16); qv2 += __shfl_xor(qv2, 32);
        if (lane < 16) {
            ps[(size_t)blk * 128 + colbase + n * 16 + cl] = sv;
            pq[(size_t)blk * 128 + colbase + n * 16 + cl] = qv2;
        }
    }
}

// ============ big pairwise GEMM 2: z3 = relu(BN2(z2)) @ W3, in place ============
__global__ __launch_bounds__(256, 4) void pair_gemm2(
    __bf16* __restrict__ Z,
    const float* __restrict__ a2, const float* __restrict__ c2,
    const __bf16* __restrict__ W3t,
    float* __restrict__ ps, float* __restrict__ pq)
{
    __shared__ __align__(16) char hA[32768];

    int blk = blockIdx.x;
    int half = blk & 1;
    int bk = blk >> 1;
    int t = threadIdx.x;
    int lane = t & 63;
    int wave = t >> 6;
    int fc = (t & 15) * 8;
    int rg = t >> 4;
    int cl = lane & 15;
    int kg = lane >> 4;
    int colbase = wave * 32;

    bf16x8 Bf[2][4];
#pragma unroll
    for (int n = 0; n < 2; ++n) {
        const __bf16* wp = W3t + (colbase + n * 16 + cl) * 128 + kg * 8;
#pragma unroll
        for (int kk = 0; kk < 4; ++kk)
            Bf[n][kk] = *reinterpret_cast<const bf16x8*>(wp + kk * 32);
    }

    float a2v[8], c2v[8];
#pragma unroll
    for (int j = 0; j < 8; ++j) { a2v[j] = a2[fc + j]; c2v[j] = c2[fc + j]; }

    __bf16* zbase = Z + ((size_t)bk * 256 + half * 128) * 128;
#pragma unroll
    for (int rr = 0; rr < 64; rr += 16) {
        int row = rr + rg;
        bf16x8 zv = *reinterpret_cast<const bf16x8*>(zbase + row * 128 + fc);
        bf16x8 v;
#pragma unroll
        for (int j = 0; j < 8; ++j)
            v[j] = (__bf16)fmaxf(a2v[j] * (float)zv[j] + c2v[j], 0.f);
        int byte = (row * 256 + fc * 2) ^ ((row & 7) << 4);
        *reinterpret_cast<bf16x8*>(hA + byte) = v;
    }
    __syncthreads();

#pragma unroll
    for (int rr = 64; rr < 128; rr += 16) {
        int row = rr + rg;
        bf16x8 zv = *reinterpret_cast<const bf16x8*>(zbase + row * 128 + fc);
        bf16x8 v;
#pragma unroll
        for (int j = 0; j < 8; ++j)
            v[j] = (__bf16)fmaxf(a2v[j] * (float)zv[j] + c2v[j], 0.f);
        int byte = (row * 256 + fc * 2) ^ ((row & 7) << 4);
        *reinterpret_cast<bf16x8*>(hA + byte) = v;
    }

    f32x4 acc[8][2] = {};
#pragma unroll
    for (int kk = 0; kk < 128; kk += 32) {
        bf16x8 af[4];
#pragma unroll
        for (int m = 0; m < 4; ++m) {
            int row = m * 16 + cl;
            int byte = (row * 256 + (kk + kg * 8) * 2) ^ ((row & 7) << 4);
            af[m] = *reinterpret_cast<const bf16x8*>(hA + byte);
        }
#pragma unroll
        for (int m = 0; m < 4; ++m)
#pragma unroll
            for (int n = 0; n < 2; ++n)
                acc[m][n] = __builtin_amdgcn_mfma_f32_16x16x32_bf16(af[m], Bf[n][kk >> 5], acc[m][n], 0, 0, 0);
    }
    __syncthreads();
#pragma unroll
    for (int kk = 0; kk < 128; kk += 32) {
        bf16x8 af[4];
#pragma unroll
        for (int m = 4; m < 8; ++m) {
            int row = m * 16 + cl;
            int byte = (row * 256 + (kk + kg * 8) * 2) ^ ((row & 7) << 4);
            af[m - 4] = *reinterpret_cast<const bf16x8*>(hA + byte);
        }
#pragma unroll
        for (int m = 4; m < 8; ++m)
#pragma unroll
            for (int n = 0; n < 2; ++n)
                acc[m][n] = __builtin_amdgcn_mfma_f32_16x16x32_bf16(af[m - 4], Bf[n][kk >> 5], acc[m][n], 0, 0, 0);
    }

    int r0 = kg * 4;
    float s[2] = {}, q[2] = {};
#pragma unroll
    for (int m = 0; m < 8; ++m)
#pragma unroll
        for (int r = 0; r < 4; ++r) {
            int row = m * 16 + r0 + r;
#pragma unroll
            for (int n = 0; n < 2; ++n) {
                float v = acc[m][n][r];
                zbase[row * 128 + colbase + n * 16 + cl] = (__bf16)v;  // z3 in place
                s[n] += v; q[n] += v * v;
            }
        }
#pragma unroll
    for (int n = 0; n < 2; ++n) {
        float sv = s[n], qv2 = q[n];
        sv += __shfl_xor(sv, 16); sv += __shfl_xor(sv, 32);
        qv2 += __shfl_xor(qv2, 16); qv2 += __shfl_xor(qv2, 32);
        if (lane < 16) {
            ps[(size_t)blk * 128 + colbase + n * 16 + cl] = sv;
            pq[(size_t)blk * 128 + colbase + n * 16 + cl] = qv2;
        }
    }
}

// ---------------- deterministic BN finalize: one block per channel ----------------
__global__ void finalize_bn(const float* __restrict__ ps, const float* __restrict__ pq,
                            int nblk, float inv_count,
                            const float* __restrict__ gamma, const float* __restrict__ beta,
                            float* __restrict__ a, float* __restrict__ c)
{
    __shared__ float rs[256], rq[256];
    int f = blockIdx.x, t = threadIdx.x;
    float s = 0, q = 0;
    for (int i = t; i < nblk; i += 256) {
        s += ps[(size_t)i * 128 + f];
        q += pq[(size_t)i * 128 + f];
    }
    rs[t] = s; rq[t] = q;
    __syncthreads();
    for (int st = 128; st > 0; st >>= 1) {
        if (t < st) { rs[t] += rs[t + st]; rq[t] += rq[t + st]; }
        __syncthreads();
    }
    if (t == 0) {
        float mean = rs[0] * inv_count;
        float var = rq[0] * inv_count - mean * mean;
        float av = gamma[f] * rsqrtf(var + 1e-5f);
        a[f] = av;
        c[f] = beta[f] - av * mean;
    }
}

// ---------------- aggregation over l (coalesced streaming) ----------------
__global__ __launch_bounds__(256) void aggregate(
    const __bf16* __restrict__ Z,
    const float* __restrict__ a3, const float* __restrict__ c3,
    const float* __restrict__ Wagg, const float* __restrict__ bagg,
    float* __restrict__ xagg)
{
    __shared__ float red[16 * 128];
    int bk = blockIdx.x;            // b*256 + k
    int t = threadIdx.x;
    int fc = t & 15;                // channel chunk (channels fc*8..+7)
    int g = t >> 4;                 // l-group 0..15
    float av[8], cv[8];
#pragma unroll
    for (int j = 0; j < 8; ++j) { av[j] = a3[fc * 8 + j]; cv[j] = c3[fc * 8 + j]; }

    const __bf16* zb = Z + (size_t)bk * 256 * 128;
    float acc[8] = {};
#pragma unroll 4
    for (int i = 0; i < 16; ++i) {
        int l = g * 16 + i;
        bf16x8 zv = *reinterpret_cast<const bf16x8*>(zb + (size_t)l * 128 + fc * 8);
        float w = Wagg[l];
#pragma unroll
        for (int j = 0; j < 8; ++j)
            acc[j] += fmaxf(av[j] * (float)zv[j] + cv[j], 0.f) * w;
    }
#pragma unroll
    for (int j = 0; j < 8; ++j) red[g * 128 + fc * 8 + j] = acc[j];
    __syncthreads();
    if (t < 128) {
        float s = 0;
#pragma unroll
        for (int gg = 0; gg < 16; ++gg) s += red[gg * 128 + t];
        xagg[(size_t)bk * 128 + t] = s + bagg[0];
    }
}

// ---------------- tail GEMM (2048x128 @ 128x128) with optional BN+relu on input ----------------
__global__ void tail_gemm(const float* __restrict__ X,
                          const float* __restrict__ aIn, const float* __restrict__ cIn, int relu_in,
                          const float* __restrict__ W, const float* __restrict__ bias,
                          float* __restrict__ Y, float* __restrict__ ps, float* __restrict__ pq)
{
    __shared__ float xs[2048];
    __shared__ float rsum[256];
    int blk = blockIdx.x, t = threadIdx.x;
    for (int i = t; i < 2048; i += 256) {
        float v = X[(size_t)blk * 2048 + i];
        if (relu_in) { int f = i & 127; v = fmaxf(aIn[f] * v + cIn[f], 0.f); }
        xs[i] = v;
    }
    __syncthreads();
    int col = t & 127, hf = t >> 7;
    float bv = bias[col];
    float acc[8];
#pragma unroll
    for (int r = 0; r < 8; ++r) acc[r] = bv;
    for (int k = 0; k < 128; ++k) {
        float w = W[k * 128 + col];
#pragma unroll
        for (int r = 0; r < 8; ++r) acc[r] += xs[(hf * 8 + r) * 128 + k] * w;
    }
    float s = 0, q = 0;
#pragma unroll
    for (int r = 0; r < 8; ++r) {
        Y[((size_t)blk * 16 + hf * 8 + r) * 128 + col] = acc[r];
        s += acc[r]; q += acc[r] * acc[r];
    }
    rsum[t] = s; __syncthreads();
    if (hf == 0) ps[(size_t)blk * 128 + col] = rsum[col] + rsum[128 + col];
    __syncthreads();
    rsum[t] = q; __syncthreads();
    if (hf == 0) pq[(size_t)blk * 128 + col] = rsum[col] + rsum[128 + col];
}

// ---------------- final layer + transpose to (b, f, d, d) ----------------
__global__ void tail_out(const float* __restrict__ Y2,
                         const float* __restrict__ ao, const float* __restrict__ co,
                         const float* __restrict__ Wo3, const float* __restrict__ bo3,
                         float* __restrict__ out)
{
    __shared__ float xs[2048];
    int blk = blockIdx.x, t = threadIdx.x;
    for (int i = t; i < 2048; i += 256) {
        int f = i & 127;
        xs[i] = fmaxf(ao[f] * Y2[(size_t)blk * 2048 + i] + co[f], 0.f);
    }
    __syncthreads();
    int col = t & 15, r = t >> 4;      // 16 rows x 16 out-channels
    float acc = bo3[col];
    for (int k = 0; k < 128; ++k) acc += xs[r * 128 + k] * Wo3[k * 16 + col];
    int grow = blk * 16 + r;           // b*256 + l
    int b = grow >> 8, l = grow & 255;
    out[((size_t)b * 16 + col) * 256 + l] = acc;
}

extern "C" void kernel_launch(void* const* d_in, const int* in_sizes, int n_in,
                              void* d_out, int out_size, void* d_ws, size_t ws_size,
                              hipStream_t stream)
{
    const float* x     = (const float*)d_in[0];
    const float* W1a   = (const float*)d_in[1];
    const float* W1b   = (const float*)d_in[2];
    const float* g1g   = (const float*)d_in[4];
    const float* g1b   = (const float*)d_in[5];
    const float* W2    = (const float*)d_in[6];
    const float* g2g   = (const float*)d_in[8];
    const float* g2b   = (const float*)d_in[9];
    const float* W3    = (const float*)d_in[10];
    const float* g3g   = (const float*)d_in[12];
    const float* g3b   = (const float*)d_in[13];
    const float* Wagg  = (const float*)d_in[14];
    const float* bagg  = (const float*)d_in[15];
    const float* Wf    = (const float*)d_in[16];
    const float* bf_   = (const float*)d_in[17];
    const float* fg    = (const float*)d_in[18];
    const float* fb    = (const float*)d_in[19];
    const float* Wo2   = (const float*)d_in[20];
    const float* bo2   = (const float*)d_in[21];
    const float* og    = (const float*)d_in[22];
    const float* ob    = (const float*)d_in[23];
    const float* Wo3   = (const float*)d_in[24];
    const float* bo3   = (const float*)d_in[25];
    const float* coord = (const float*)d_in[26];

    char* ws = (char*)d_ws;
    float*  HI   = (float*)(ws + HI_OFF);
    float*  HJ   = (float*)(ws + HJ_OFF);
    __bf16* Z    = (__bf16*)(ws + Z_OFF);
    float*  PS   = (float*)(ws + PS_OFF);
    float*  PQ   = (float*)(ws + PQ_OFF);
    float*  S1I  = (float*)(ws + S1I_OFF);
    float*  S2I  = (float*)(ws + S2I_OFF);
    float*  S1J  = (float*)(ws + S1J_OFF);
    float*  S2J  = (float*)(ws + S2J_OFF);
    float*  A1   = (float*)(ws + A1_OFF);
    float*  D1   = (float*)(ws + D1_OFF);
    float*  A2   = (float*)(ws + A2_OFF);
    float*  C2   = (float*)(ws + C2_OFF);
    float*  A3   = (float*)(ws + A3_OFF);
    float*  C3   = (float*)(ws + C3_OFF);
    float*  AF   = (float*)(ws + AF_OFF);
    float*  CF   = (float*)(ws + CF_OFF);
    float*  AO   = (float*)(ws + AO_OFF);
    float*  CO   = (float*)(ws + CO_OFF);
    __bf16* W2T  = (__bf16*)(ws + W2T_OFF);
    __bf16* W3T  = (__bf16*)(ws + W3T_OFF);
    float*  XAGG = (float*)(ws + XAGG_OFF);
    float*  Y1   = (float*)(ws + Y1_OFF);
    float*  Y2   = (float*)(ws + Y2_OFF);
    float*  TPS  = (float*)(ws + TPS_OFF);
    float*  TPQ  = (float*)(ws + TPQ_OFF);

    build_h<<<2048, 128, 0, stream>>>(x, coord, W1a, W1b, HI, HJ);
    stats1<<<64, 128, 0, stream>>>(HI, HJ, S1I, S2I, S1J, S2J);
    bn1_finalize<<<1, 128, 0, stream>>>(S1I, S2I, S1J, S2J, g1g, g1b, A1, D1);
    transpose_w<<<128, 128, 0, stream>>>(W2, W3, W2T, W3T);

    pair_gemm1<<<4096, 256, 0, stream>>>(HI, HJ, A1, D1, W2T, Z, PS, PQ);
    finalize_bn<<<128, 256, 0, stream>>>(PS, PQ, 4096, 1.f / 524288.f, g2g, g2b, A2, C2);

    pair_gemm2<<<4096, 256, 0, stream>>>(Z, A2, C2, W3T, PS, PQ);
    finalize_bn<<<128, 256, 0, stream>>>(PS, PQ, 4096, 1.f / 524288.f, g3g, g3b, A3, C3);

    aggregate<<<2048, 256, 0, stream>>>(Z, A3, C3, Wagg, bagg, XAGG);

    tail_gemm<<<128, 256, 0, stream>>>(XAGG, A1, D1, 0, Wf, bf_, Y1, TPS, TPQ);
    finalize_bn<<<128, 256, 0, stream>>>(TPS, TPQ, 128, 1.f / 2048.f, fg, fb, AF, CF);

    tail_gemm<<<128, 256, 0, stream>>>(Y1, AF, CF, 1, Wo2, bo2, Y2, TPS, TPQ);
    finalize_bn<<<128, 256, 0, stream>>>(TPS, TPQ, 128, 1.f / 2048.f, og, ob, AO, CO);

    tail_out<<<128, 256, 0, stream>>>(Y2, AO, CO, Wo3, bo3, (float*)d_out);

    (void)in_sizes; (void)n_in; (void)out_size; (void)ws_size;
}

// Round 16
// 189.092 us; speedup vs baseline: 1.0274x; 1.0274x over previous
//
#include <hip/hip_runtime.h>
#include <hip/hip_bf16.h>

typedef __bf16 bf16x8 __attribute__((ext_vector_type(8)));
typedef float  f32x4  __attribute__((ext_vector_type(4)));

// ---------------- workspace layout (bytes) ----------------
static constexpr size_t MB = 1u << 20;
static constexpr size_t HI_OFF  = 0;                                   // 1 MiB
static constexpr size_t HJ_OFF  = HI_OFF + MB;
static constexpr size_t Z_OFF   = HJ_OFF + MB;                         // 128 MiB (z2, then z3 in place)
static constexpr size_t PS_OFF  = Z_OFF + (size_t)524288 * 128 * 2;    // 4096*128*4 = 2 MiB
static constexpr size_t PQ_OFF  = PS_OFF + (size_t)4096 * 128 * 4;
static constexpr size_t S1I_OFF = PQ_OFF + (size_t)4096 * 128 * 4;     // 64*128*4 = 32 KiB each
static constexpr size_t S2I_OFF = S1I_OFF + 32768;
static constexpr size_t S1J_OFF = S2I_OFF + 32768;
static constexpr size_t S2J_OFF = S1J_OFF + 32768;
static constexpr size_t A1_OFF  = S2J_OFF + 32768;                     // 512 each
static constexpr size_t D1_OFF  = A1_OFF + 512;
static constexpr size_t A2_OFF  = D1_OFF + 512;
static constexpr size_t C2_OFF  = A2_OFF + 512;
static constexpr size_t A3_OFF  = C2_OFF + 512;
static constexpr size_t C3_OFF  = A3_OFF + 512;
static constexpr size_t AF_OFF  = C3_OFF + 512;
static constexpr size_t CF_OFF  = AF_OFF + 512;
static constexpr size_t AO_OFF  = CF_OFF + 512;
static constexpr size_t CO_OFF  = AO_OFF + 512;
static constexpr size_t W2T_OFF = CO_OFF + 512;                        // 32 KiB
static constexpr size_t W3T_OFF = W2T_OFF + 32768;
static constexpr size_t Y1_OFF  = W3T_OFF + 32768;                     // 1 MiB
static constexpr size_t Y2_OFF  = Y1_OFF + MB;
static constexpr size_t TPS_OFF = Y2_OFF + MB;                         // 64 KiB
static constexpr size_t TPQ_OFF = TPS_OFF + 65536;

// ---------------- K1 (fused): hi/hj + per-(b,lg) BN1 moments ----------------
__global__ void build_stats(const float* __restrict__ x, const float* __restrict__ coord,
                            const float* __restrict__ W1a, const float* __restrict__ W1b,
                            float* __restrict__ hi, float* __restrict__ hj,
                            float* __restrict__ S1i, float* __restrict__ S2i,
                            float* __restrict__ S1j, float* __restrict__ S2j)
{
    __shared__ float xls[16][32];
    __shared__ float cls[32][2];
    int g = blockIdx.x;             // b*8 + lg
    int b = g >> 3, lg = g & 7;
    int t = threadIdx.x;            // 128 = channel f
    for (int i = t; i < 512; i += 128) {
        int c = i >> 5, l = i & 31;
        xls[c][l] = x[((size_t)(b * 16 + c)) * 256 + lg * 32 + l];
    }
    if (t < 64) cls[t >> 1][t & 1] = coord[(lg * 32 + (t >> 1)) * 2 + (t & 1)];
    __syncthreads();

    float wa[18], wb[18];
#pragma unroll
    for (int c = 0; c < 18; ++c) { wa[c] = W1a[c * 128 + t]; wb[c] = W1b[c * 128 + t]; }

    float s1i = 0, s2i = 0, s1j = 0, s2j = 0;
    for (int l = 0; l < 32; ++l) {
        float ai = 0.f, aj = 0.f;
#pragma unroll
        for (int c = 0; c < 16; ++c) { float xv = xls[c][l]; ai += xv * wa[c]; aj += xv * wb[c]; }
#pragma unroll
        for (int c = 0; c < 2; ++c)  { float xv = cls[l][c]; ai += xv * wa[16 + c]; aj += xv * wb[16 + c]; }
        size_t row = (size_t)b * 256 + lg * 32 + l;
        hi[row * 128 + t] = ai;
        hj[row * 128 + t] = aj;
        s1i += ai; s2i += ai * ai;
        s1j += aj; s2j += aj * aj;
    }
    S1i[g * 128 + t] = s1i; S2i[g * 128 + t] = s2i;
    S1j[g * 128 + t] = s1j; S2j[g * 128 + t] = s2j;
}

// ---------------- K2 (merged): weight transpose (all blocks) + BN1 closed-form (block 0) ----------------
__global__ void bn1_tw(const float* __restrict__ S1i, const float* __restrict__ S2i,
                       const float* __restrict__ S1j, const float* __restrict__ S2j,
                       const float* __restrict__ g, const float* __restrict__ be,
                       float* __restrict__ a1, float* __restrict__ d1,
                       const float* __restrict__ W2, const float* __restrict__ W3,
                       __bf16* __restrict__ W2t, __bf16* __restrict__ W3t)
{
    int f = blockIdx.x, k = threadIdx.x;   // Wt[f][k] = W[k][f]
    W2t[f * 128 + k] = (__bf16)W2[k * 128 + f];
    W3t[f * 128 + k] = (__bf16)W3[k * 128 + f];

    if (blockIdx.x == 0) {
        int ff = threadIdx.x;  // 128
        float s1i = 0, s2i = 0, s1j = 0, s2j = 0;
        float mib[8], mjb[8];
#pragma unroll
        for (int b = 0; b < 8; ++b) {
            float sb = 0, sbj = 0;
#pragma unroll
            for (int lg = 0; lg < 8; ++lg) {
                int gg = b * 8 + lg;
                sb  += S1i[gg * 128 + ff]; s2i += S2i[gg * 128 + ff];
                sbj += S1j[gg * 128 + ff]; s2j += S2j[gg * 128 + ff];
            }
            mib[b] = sb * (1.f / 256.f); mjb[b] = sbj * (1.f / 256.f);
            s1i += sb; s1j += sbj;
        }
        const float invN = 1.f / 2048.f;
        float mi = s1i * invN, mj = s1j * invN;
        float vu = s2i * invN - mi * mi;
        float vv = s2j * invN - mj * mj;
        float cr = 0.f;
#pragma unroll
        for (int b = 0; b < 8; ++b) cr += (mib[b] - mi) * (mjb[b] - mj);
        cr *= (1.f / 8.f);
        float var = vu + vv + 2.f * cr;
        float av = g[ff] * rsqrtf(var + 1e-5f);
        a1[ff] = av;
        d1[ff] = be[ff] - av * (mi + mj);   // b1 cancels (BN shift invariance)
    }
}

// ============ big pairwise GEMM 1 (round-14 verbatim): z2 = relu(BN1(hi[l]+hj[k])) @ W2 ============
__global__ __launch_bounds__(256, 4) void pair_gemm1(
    const float* __restrict__ hi, const float* __restrict__ hj,
    const float* __restrict__ a1, const float* __restrict__ d1,
    const __bf16* __restrict__ W2t,
    __bf16* __restrict__ Z, float* __restrict__ ps, float* __restrict__ pq)
{
    __shared__ __align__(16) char hA[32768];   // 128x128 bf16, XOR-swizzled

    int blk = blockIdx.x;
    int half = blk & 1;
    int bk = blk >> 1;             // b*256 + k
    int b = bk >> 8;
    int t = threadIdx.x;
    int lane = t & 63;
    int wave = t >> 6;
    int fc = (t & 15) * 8;         // staging channel chunk
    int rg = t >> 4;               // staging row group 0..15
    int cl = lane & 15;
    int kg = lane >> 4;            // 0..3
    int colbase = wave * 32;

    // B fragments (hoisted; latency overlaps staging below)
    bf16x8 Bf[2][4];
#pragma unroll
    for (int n = 0; n < 2; ++n) {
        const __bf16* wp = W2t + (colbase + n * 16 + cl) * 128 + kg * 8;
#pragma unroll
        for (int kk = 0; kk < 4; ++kk)
            Bf[n][kk] = *reinterpret_cast<const bf16x8*>(wp + kk * 32);
    }

    float a1v[8], qv[8];
    const float* hjrow = hj + (size_t)bk * 128 + fc;
    const float* d1p = d1 + fc;
    const float* a1p = a1 + fc;
#pragma unroll
    for (int j = 0; j < 8; ++j) { a1v[j] = a1p[j]; qv[j] = a1v[j] * hjrow[j] + d1p[j]; }

    const float* hib = hi + ((size_t)b * 256 + half * 128) * 128;
#pragma unroll
    for (int rr = 0; rr < 128; rr += 16) {
        int row = rr + rg;
        const float* src = hib + row * 128 + fc;
        bf16x8 v;
#pragma unroll
        for (int j = 0; j < 8; ++j) {
            float h = fmaxf(a1v[j] * src[j] + qv[j], 0.f);
            v[j] = (__bf16)h;
        }
        int byte = (row * 256 + fc * 2) ^ ((row & 7) << 4);
        *reinterpret_cast<bf16x8*>(hA + byte) = v;
    }
    __syncthreads();

    f32x4 acc[8][2] = {};
#pragma unroll
    for (int kk = 0; kk < 128; kk += 32) {
        bf16x8 af[8];
#pragma unroll
        for (int m = 0; m < 8; ++m) {
            int row = m * 16 + cl;
            int byte = (row * 256 + (kk + kg * 8) * 2) ^ ((row & 7) << 4);
            af[m] = *reinterpret_cast<const bf16x8*>(hA + byte);
        }
#pragma unroll
        for (int m = 0; m < 8; ++m)
#pragma unroll
            for (int n = 0; n < 2; ++n)
                acc[m][n] = __builtin_amdgcn_mfma_f32_16x16x32_bf16(af[m], Bf[n][kk >> 5], acc[m][n], 0, 0, 0);
    }

    // epilogue: line-friendly order (both 32B halves of each 64B region back-to-back)
    __bf16* zb = Z + ((size_t)bk * 256 + half * 128) * 128;
    int r0 = kg * 4;
    float s[2] = {}, q[2] = {};
#pragma unroll
    for (int m = 0; m < 8; ++m)
#pragma unroll
        for (int r = 0; r < 4; ++r) {
            int row = m * 16 + r0 + r;
#pragma unroll
            for (int n = 0; n < 2; ++n) {
                float v = acc[m][n][r];
                zb[row * 128 + colbase + n * 16 + cl] = (__bf16)v;
                s[n] += v; q[n] += v * v;
            }
        }
#pragma unroll
    for (int n = 0; n < 2; ++n) {
        float sv = s[n], qv2 = q[n];
        sv += __shfl_xor(sv, 16); sv += __shfl_xor(sv, 32);
        qv2 += __shfl_xor(qv2, 16); qv2 += __shfl_xor(qv2, 32);
        if (lane < 16) {
            ps[(size_t)blk * 128 + colbase + n * 16 + cl] = sv;
            pq[(size_t)blk * 128 + colbase + n * 16 + cl] = qv2;
        }
    }
}

// ============ big pairwise GEMM 2 (round-14 verbatim): z3 = relu(BN2(z2)) @ W3, in place ============
__global__ __launch_bounds__(256, 4) void pair_gemm2(
    __bf16* __restrict__ Z,
    const float* __restrict__ a2, const float* __restrict__ c2,
    const __bf16* __restrict__ W3t,
    float* __restrict__ ps, float* __restrict__ pq)
{
    __shared__ __align__(16) char hA[32768];

    int blk = blockIdx.x;
    int half = blk & 1;
    int bk = blk >> 1;
    int t = threadIdx.x;
    int lane = t & 63;
    int wave = t >> 6;
    int fc = (t & 15) * 8;
    int rg = t >> 4;
    int cl = lane & 15;
    int kg = lane >> 4;
    int colbase = wave * 32;

    bf16x8 Bf[2][4];
#pragma unroll
    for (int n = 0; n < 2; ++n) {
        const __bf16* wp = W3t + (colbase + n * 16 + cl) * 128 + kg * 8;
#pragma unroll
        for (int kk = 0; kk < 4; ++kk)
            Bf[n][kk] = *reinterpret_cast<const bf16x8*>(wp + kk * 32);
    }

    float a2v[8], c2v[8];
#pragma unroll
    for (int j = 0; j < 8; ++j) { a2v[j] = a2[fc + j]; c2v[j] = c2[fc + j]; }

    __bf16* zbase = Z + ((size_t)bk * 256 + half * 128) * 128;
#pragma unroll
    for (int rr = 0; rr < 128; rr += 16) {
        int row = rr + rg;
        bf16x8 zv = *reinterpret_cast<const bf16x8*>(zbase + row * 128 + fc);
        bf16x8 v;
#pragma unroll
        for (int j = 0; j < 8; ++j) {
            float h = fmaxf(a2v[j] * (float)zv[j] + c2v[j], 0.f);
            v[j] = (__bf16)h;
        }
        int byte = (row * 256 + fc * 2) ^ ((row & 7) << 4);
        *reinterpret_cast<bf16x8*>(hA + byte) = v;
    }
    __syncthreads();

    f32x4 acc[8][2] = {};
#pragma unroll
    for (int kk = 0; kk < 128; kk += 32) {
        bf16x8 af[8];
#pragma unroll
        for (int m = 0; m < 8; ++m) {
            int row = m * 16 + cl;
            int byte = (row * 256 + (kk + kg * 8) * 2) ^ ((row & 7) << 4);
            af[m] = *reinterpret_cast<const bf16x8*>(hA + byte);
        }
#pragma unroll
        for (int m = 0; m < 8; ++m)
#pragma unroll
            for (int n = 0; n < 2; ++n)
                acc[m][n] = __builtin_amdgcn_mfma_f32_16x16x32_bf16(af[m], Bf[n][kk >> 5], acc[m][n], 0, 0, 0);
    }

    int r0 = kg * 4;
    float s[2] = {}, q[2] = {};
#pragma unroll
    for (int m = 0; m < 8; ++m)
#pragma unroll
        for (int r = 0; r < 4; ++r) {
            int row = m * 16 + r0 + r;
#pragma unroll
            for (int n = 0; n < 2; ++n) {
                float v = acc[m][n][r];
                zbase[row * 128 + colbase + n * 16 + cl] = (__bf16)v;  // z3 in place
                s[n] += v; q[n] += v * v;
            }
        }
#pragma unroll
    for (int n = 0; n < 2; ++n) {
        float sv = s[n], qv2 = q[n];
        sv += __shfl_xor(sv, 16); sv += __shfl_xor(sv, 32);
        qv2 += __shfl_xor(qv2, 16); qv2 += __shfl_xor(qv2, 32);
        if (lane < 16) {
            ps[(size_t)blk * 128 + colbase + n * 16 + cl] = sv;
            pq[(size_t)blk * 128 + colbase + n * 16 + cl] = qv2;
        }
    }
}

// ---------------- deterministic BN finalize: one block per channel ----------------
__global__ void finalize_bn(const float* __restrict__ ps, const float* __restrict__ pq,
                            int nblk, float inv_count,
                            const float* __restrict__ gamma, const float* __restrict__ beta,
                            float* __restrict__ a, float* __restrict__ c)
{
    __shared__ float rs[256], rq[256];
    int f = blockIdx.x, t = threadIdx.x;
    float s = 0, q = 0;
    for (int i = t; i < nblk; i += 256) {
        s += ps[(size_t)i * 128 + f];
        q += pq[(size_t)i * 128 + f];
    }
    rs[t] = s; rq[t] = q;
    __syncthreads();
    for (int st = 128; st > 0; st >>= 1) {
        if (t < st) { rs[t] += rs[t + st]; rq[t] += rq[t + st]; }
        __syncthreads();
    }
    if (t == 0) {
        float mean = rs[0] * inv_count;
        float var = rq[0] * inv_count - mean * mean;
        float av = gamma[f] * rsqrtf(var + 1e-5f);
        a[f] = av;
        c[f] = beta[f] - av * mean;
    }
}

// ---------------- fused: aggregate over l  +  y1 = xagg @ Wf + bf (with BN-f partials) ----------------
__global__ __launch_bounds__(256) void aggregate_tail(
    const __bf16* __restrict__ Z,
    const float* __restrict__ a3, const float* __restrict__ c3,
    const float* __restrict__ Wagg, const float* __restrict__ bagg,
    const float* __restrict__ Wf, const float* __restrict__ bf_,
    float* __restrict__ Y1, float* __restrict__ ps, float* __restrict__ pq)
{
    __shared__ float red[16 * 128];
    __shared__ float xs[128];
    __shared__ float red2[256];

    int bk = blockIdx.x;            // b*256 + k
    int t = threadIdx.x;
    int fc = t & 15;                // channel chunk (channels fc*8..+7)
    int g = t >> 4;                 // l-group 0..15
    float av[8], cv[8];
#pragma unroll
    for (int j = 0; j < 8; ++j) { av[j] = a3[fc * 8 + j]; cv[j] = c3[fc * 8 + j]; }

    const __bf16* zb = Z + (size_t)bk * 256 * 128;
    float acc[8] = {};
#pragma unroll 4
    for (int i = 0; i < 16; ++i) {
        int l = g * 16 + i;
        bf16x8 zv = *reinterpret_cast<const bf16x8*>(zb + (size_t)l * 128 + fc * 8);
        float w = Wagg[l];
#pragma unroll
        for (int j = 0; j < 8; ++j)
            acc[j] += fmaxf(av[j] * (float)zv[j] + cv[j], 0.f) * w;
    }
#pragma unroll
    for (int j = 0; j < 8; ++j) red[g * 128 + fc * 8 + j] = acc[j];
    __syncthreads();
    if (t < 128) {
        float s = 0;
#pragma unroll
        for (int gg = 0; gg < 16; ++gg) s += red[gg * 128 + t];
        xs[t] = s + bagg[0];
    }
    __syncthreads();

    // y1[col] = sum_k xs[k] * Wf[k][col] + bf[col]; 2 half-K slices per column
    int col = t & 127, hf = t >> 7;
    float d = 0.f;
#pragma unroll 4
    for (int k = hf * 64; k < hf * 64 + 64; ++k)
        d += xs[k] * Wf[k * 128 + col];
    red2[t] = d;
    __syncthreads();
    if (hf == 0) {
        float y = red2[col] + red2[128 + col] + bf_[col];
        Y1[(size_t)bk * 128 + col] = y;
        ps[(size_t)bk * 128 + col] = y;
        pq[(size_t)bk * 128 + col] = y * y;
    }
}

// ---------------- tail GEMM (2048x128 @ 128x128) with BN+relu on input ----------------
__global__ void tail_gemm(const float* __restrict__ X,
                          const float* __restrict__ aIn, const float* __restrict__ cIn,
                          const float* __restrict__ W, const float* __restrict__ bias,
                          float* __restrict__ Y, float* __restrict__ ps, float* __restrict__ pq)
{
    __shared__ float xs[2048];
    __shared__ float rsum[256];
    int blk = blockIdx.x, t = threadIdx.x;
    for (int i = t; i < 2048; i += 256) {
        int f = i & 127;
        xs[i] = fmaxf(aIn[f] * X[(size_t)blk * 2048 + i] + cIn[f], 0.f);
    }
    __syncthreads();
    int col = t & 127, hf = t >> 7;
    float bv = bias[col];
    float acc[8];
#pragma unroll
    for (int r = 0; r < 8; ++r) acc[r] = bv;
    for (int k = 0; k < 128; ++k) {
        float w = W[k * 128 + col];
#pragma unroll
        for (int r = 0; r < 8; ++r) acc[r] += xs[(hf * 8 + r) * 128 + k] * w;
    }
    float s = 0, q = 0;
#pragma unroll
    for (int r = 0; r < 8; ++r) {
        Y[((size_t)blk * 16 + hf * 8 + r) * 128 + col] = acc[r];
        s += acc[r]; q += acc[r] * acc[r];
    }
    rsum[t] = s; __syncthreads();
    if (hf == 0) ps[(size_t)blk * 128 + col] = rsum[col] + rsum[128 + col];
    __syncthreads();
    rsum[t] = q; __syncthreads();
    if (hf == 0) pq[(size_t)blk * 128 + col] = rsum[col] + rsum[128 + col];
}

// ---------------- final layer + transpose to (b, f, d, d) ----------------
__global__ void tail_out(const float* __restrict__ Y2,
                         const float* __restrict__ ao, const float* __restrict__ co,
                         const float* __restrict__ Wo3, const float* __restrict__ bo3,
                         float* __restrict__ out)
{
    __shared__ float xs[2048];
    int blk = blockIdx.x, t = threadIdx.x;
    for (int i = t; i < 2048; i += 256) {
        int f = i & 127;
        xs[i] = fmaxf(ao[f] * Y2[(size_t)blk * 2048 + i] + co[f], 0.f);
    }
    __syncthreads();
    int col = t & 15, r = t >> 4;      // 16 rows x 16 out-channels
    float acc = bo3[col];
    for (int k = 0; k < 128; ++k) acc += xs[r * 128 + k] * Wo3[k * 16 + col];
    int grow = blk * 16 + r;           // b*256 + l
    int b = grow >> 8, l = grow & 255;
    out[((size_t)b * 16 + col) * 256 + l] = acc;
}

extern "C" void kernel_launch(void* const* d_in, const int* in_sizes, int n_in,
                              void* d_out, int out_size, void* d_ws, size_t ws_size,
                              hipStream_t stream)
{
    const float* x     = (const float*)d_in[0];
    const float* W1a   = (const float*)d_in[1];
    const float* W1b   = (const float*)d_in[2];
    const float* g1g   = (const float*)d_in[4];
    const float* g1b   = (const float*)d_in[5];
    const float* W2    = (const float*)d_in[6];
    const float* g2g   = (const float*)d_in[8];
    const float* g2b   = (const float*)d_in[9];
    const float* W3    = (const float*)d_in[10];
    const float* g3g   = (const float*)d_in[12];
    const float* g3b   = (const float*)d_in[13];
    const float* Wagg  = (const float*)d_in[14];
    const float* bagg  = (const float*)d_in[15];
    const float* Wf    = (const float*)d_in[16];
    const float* bf_   = (const float*)d_in[17];
    const float* fg    = (const float*)d_in[18];
    const float* fb    = (const float*)d_in[19];
    const float* Wo2   = (const float*)d_in[20];
    const float* bo2   = (const float*)d_in[21];
    const float* og    = (const float*)d_in[22];
    const float* ob    = (const float*)d_in[23];
    const float* Wo3   = (const float*)d_in[24];
    const float* bo3   = (const float*)d_in[25];
    const float* coord = (const float*)d_in[26];

    char* ws = (char*)d_ws;
    float*  HI   = (float*)(ws + HI_OFF);
    float*  HJ   = (float*)(ws + HJ_OFF);
    __bf16* Z    = (__bf16*)(ws + Z_OFF);
    float*  PS   = (float*)(ws + PS_OFF);
    float*  PQ   = (float*)(ws + PQ_OFF);
    float*  S1I  = (float*)(ws + S1I_OFF);
    float*  S2I  = (float*)(ws + S2I_OFF);
    float*  S1J  = (float*)(ws + S1J_OFF);
    float*  S2J  = (float*)(ws + S2J_OFF);
    float*  A1   = (float*)(ws + A1_OFF);
    float*  D1   = (float*)(ws + D1_OFF);
    float*  A2   = (float*)(ws + A2_OFF);
    float*  C2   = (float*)(ws + C2_OFF);
    float*  A3   = (float*)(ws + A3_OFF);
    float*  C3   = (float*)(ws + C3_OFF);
    float*  AF   = (float*)(ws + AF_OFF);
    float*  CF   = (float*)(ws + CF_OFF);
    float*  AO   = (float*)(ws + AO_OFF);
    float*  CO   = (float*)(ws + CO_OFF);
    __bf16* W2T  = (__bf16*)(ws + W2T_OFF);
    __bf16* W3T  = (__bf16*)(ws + W3T_OFF);
    float*  Y1   = (float*)(ws + Y1_OFF);
    float*  Y2   = (float*)(ws + Y2_OFF);
    float*  TPS  = (float*)(ws + TPS_OFF);
    float*  TPQ  = (float*)(ws + TPQ_OFF);

    build_stats<<<64, 128, 0, stream>>>(x, coord, W1a, W1b, HI, HJ, S1I, S2I, S1J, S2J);
    bn1_tw<<<128, 128, 0, stream>>>(S1I, S2I, S1J, S2J, g1g, g1b, A1, D1, W2, W3, W2T, W3T);

    pair_gemm1<<<4096, 256, 0, stream>>>(HI, HJ, A1, D1, W2T, Z, PS, PQ);
    finalize_bn<<<128, 256, 0, stream>>>(PS, PQ, 4096, 1.f / 524288.f, g2g, g2b, A2, C2);

    pair_gemm2<<<4096, 256, 0, stream>>>(Z, A2, C2, W3T, PS, PQ);
    finalize_bn<<<128, 256, 0, stream>>>(PS, PQ, 4096, 1.f / 524288.f, g3g, g3b, A3, C3);

    aggregate_tail<<<2048, 256, 0, stream>>>(Z, A3, C3, Wagg, bagg, Wf, bf_, Y1, PS, PQ);
    finalize_bn<<<128, 256, 0, stream>>>(PS, PQ, 2048, 1.f / 2048.f, fg, fb, AF, CF);

    tail_gemm<<<128, 256, 0, stream>>>(Y1, AF, CF, Wo2, bo2, Y2, TPS, TPQ);
    finalize_bn<<<128, 256, 0, stream>>>(TPS, TPQ, 128, 1.f / 2048.f, og, ob, AO, CO);

    tail_out<<<128, 256, 0, stream>>>(Y2, AO, CO, Wo3, bo3, (float*)d_out);

    (void)in_sizes; (void)n_in; (void)out_size; (void)ws_size;
}